// Round 18
// baseline (137.221 us; speedup 1.0000x reference)
//
#include <hip/hip_runtime.h>
#include <stdint.h>

typedef unsigned short u16;
typedef short bf16x8 __attribute__((ext_vector_type(8)));
typedef float f32x4 __attribute__((ext_vector_type(4)));

#define ABI 8
#define BSZ 128
#define INF 4096
#define OUTF 4096
#define LRK 64
#define KT2 1280          // Wb2 row stride; k layout: band + [1152,1216) LR
#define NST 16

__device__ __forceinline__ u16 f2bf(float f) {
    uint32_t u = __float_as_uint(f);
    u += 0x7fffu + ((u >> 16) & 1u);
    return (u16)(u >> 16);
}

__device__ __forceinline__ uint32_t pk2(float a, float b) {
    uint32_t r;
    asm("v_cvt_pk_bf16_f32 %0, %1, %2" : "=v"(r) : "v"(a), "v"(b));
    return r;
}

__device__ __forceinline__ void async16(const u16* g, u16* l) {
    __builtin_amdgcn_global_load_lds(
        (const __attribute__((address_space(1))) uint32_t*)g,
        (__attribute__((address_space(3))) uint32_t*)l, 16, 0, 0);
}

#define FENCE() asm volatile("" ::: "memory")

// ---------------------------------------------------------------------------
// Kernel 1: L1 -> L1b bf16 (tiny; precedes gm_main which reads L1b).
// ---------------------------------------------------------------------------
__global__ __launch_bounds__(256) void gm_l1b(
        const float* __restrict__ L1, u16* __restrict__ L1b) {
    int idx = (blockIdx.x * 256 + threadIdx.x) * 4;
    f32x4 v = *reinterpret_cast<const f32x4*>(L1 + idx);
    uint32_t lo = pk2(v[0], v[1]);
    uint32_t hi = pk2(v[2], v[3]);
    *reinterpret_cast<uint32_t*>(L1b + idx)     = lo;
    *reinterpret_cast<uint32_t*>(L1b + idx + 2) = hi;
}

// ---------------------------------------------------------------------------
// Kernel 2: merged pack + cast. __launch_bounds__(256, 2): min 2 waves/EU
// (= 2 blocks/CU = the grid cap) -> VGPR budget up to 256, so the cast
// role's 1-deep prefetch (x + 4 bv loads) can stay LIVE in registers
// (r8/r13 failed at VGPR 36-44 because default bounds targeted 8 waves/EU).
// bid [0,256): W transpose | [256,288): L2 pack | [288,800): cast+h.
// ---------------------------------------------------------------------------
__global__ __launch_bounds__(256, 2) void gm_main(
        const float* __restrict__ x, const float* __restrict__ W,
        const float* __restrict__ L2, const u16* __restrict__ L1b,
        u16* __restrict__ xb, u16* __restrict__ hb, u16* __restrict__ Wb2) {
    __shared__ char shm[32768];
    int bid = blockIdx.x;
    int t = threadIdx.x;
    if (bid < 256) {
        u16* tile = (u16*)shm;                 // 128*128 u16 = 32 KB
        int j = bid & 7, o = bid >> 3;
        int os = o >> 1, hh = o & 1;
        int i = (o + 25 + j) & 31;             // (o-7+j) mod 32
        int a = 7 - j;
        int c = t & 127, b0 = t >> 7;          // b0: 0..1
        const float* src = W + ((size_t)(i * BSZ) * ABI + a) * BSZ + c;
#pragma unroll 4
        for (int p = 0; p < 64; ++p) {
            int b = p * 2 + b0;
            tile[b * 128 + (c ^ ((b & 31) << 1))] =
                f2bf(src[(size_t)b * (ABI * BSZ)]);
        }
        __syncthreads();
        int b = t & 127, c0 = t >> 7;
        u16* dst = Wb2 + ((size_t)os * 256 + hh * 128) * KT2
                 + (size_t)(hh * 128 + j * 128 + b);
#pragma unroll 4
        for (int p = 0; p < 64; ++p) {
            int cc = p * 2 + c0;
            dst[(size_t)cc * KT2] = tile[b * 128 + (cc ^ ((b & 31) << 1))];
        }
    } else if (bid < 288) {
        int o = bid - 256;
        int os = o >> 1, hh = o & 1;
        int r = t & 63, c0 = t >> 6;           // c0: 0..3
#pragma unroll 4
        for (int p = 0; p < 32; ++p) {
            int c = p * 4 + c0;
            Wb2[((size_t)os * 256 + hh * 128 + c) * KT2 + 1152 + r] =
                f2bf(L2[((size_t)o * BSZ + c) * LRK + r]);
        }
    } else {
        // ---- cast role: r12 body + 1-deep prefetch (x AND bv), now with
        // the VGPR budget to keep it live.
        float* red = (float*)shm;              // [4][4][256] = 16 KB
        int w = t >> 6, lane = t & 63;
        int lr = lane & 15, lk = (lane >> 4) << 3;
        int rb = (bid - 288) * 16;
        int row = rb + lr;
        const float* xp = x + (size_t)row * INF + w * 1024 + lk;
        u16* xo = xb + (size_t)row * INF + w * 1024 + lk;
        const u16* lp = L1b + (size_t)lr * INF + w * 1024 + lk;
        f32x4 acc[4];
#pragma unroll
        for (int ni = 0; ni < 4; ++ni) acc[ni] = (f32x4){0.f, 0.f, 0.f, 0.f};
        f32x4 c0 = *(const f32x4*)xp;
        f32x4 c1 = *(const f32x4*)(xp + 4);
        bf16x8 bv0 = *(const bf16x8*)(lp + 0 * 16 * INF);
        bf16x8 bv1 = *(const bf16x8*)(lp + 1 * 16 * INF);
        bf16x8 bv2 = *(const bf16x8*)(lp + 2 * 16 * INF);
        bf16x8 bv3 = *(const bf16x8*)(lp + 3 * 16 * INF);
        for (int ks = 0; ks < 32; ++ks) {
            f32x4 n0 = c0, n1 = c1;
            bf16x8 nb0 = bv0, nb1 = bv1, nb2 = bv2, nb3 = bv3;
            if (ks < 31) {
                const float* xn = xp + (ks + 1) * 32;
                n0 = *(const f32x4*)xn;
                n1 = *(const f32x4*)(xn + 4);
                const u16* ln = lp + (ks + 1) * 32;
                nb0 = *(const bf16x8*)(ln + 0 * 16 * INF);
                nb1 = *(const bf16x8*)(ln + 1 * 16 * INF);
                nb2 = *(const bf16x8*)(ln + 2 * 16 * INF);
                nb3 = *(const bf16x8*)(ln + 3 * 16 * INF);
            }
            union { bf16x8 v; uint32_t u[4]; } af;
            af.u[0] = pk2(c0[0], c0[1]);
            af.u[1] = pk2(c0[2], c0[3]);
            af.u[2] = pk2(c1[0], c1[1]);
            af.u[3] = pk2(c1[2], c1[3]);
            *reinterpret_cast<bf16x8*>(xo + ks * 32) = af.v;
            acc[0] = __builtin_amdgcn_mfma_f32_16x16x32_bf16(af.v, bv0, acc[0], 0, 0, 0);
            acc[1] = __builtin_amdgcn_mfma_f32_16x16x32_bf16(af.v, bv1, acc[1], 0, 0, 0);
            acc[2] = __builtin_amdgcn_mfma_f32_16x16x32_bf16(af.v, bv2, acc[2], 0, 0, 0);
            acc[3] = __builtin_amdgcn_mfma_f32_16x16x32_bf16(af.v, bv3, acc[3], 0, 0, 0);
            c0 = n0; c1 = n1;
            bv0 = nb0; bv1 = nb1; bv2 = nb2; bv3 = nb3;
        }
#pragma unroll
        for (int ni = 0; ni < 4; ++ni)
#pragma unroll
            for (int j = 0; j < 4; ++j)
                red[(w * 4 + ni) * 256 + lane * 4 + j] = acc[ni][j];
        __syncthreads();
        if (t < 64) {
#pragma unroll
            for (int ni = 0; ni < 4; ++ni)
#pragma unroll
                for (int j = 0; j < 4; ++j) {
                    float s = red[(0 * 4 + ni) * 256 + t * 4 + j]
                            + red[(1 * 4 + ni) * 256 + t * 4 + j]
                            + red[(2 * 4 + ni) * 256 + t * 4 + j]
                            + red[(3 * 4 + ni) * 256 + t * 4 + j];
                    int r_ = rb + ((t >> 4) << 2) + j;
                    int c_ = ni * 16 + (t & 15);
                    hb[(size_t)r_ * LRK + c_] = f2bf(s);
                }
        }
    }
}

// ---------------------------------------------------------------------------
// Kernel 3: 256x256 GEMM — EXACT r14/r17 version (best measured). 4-phase
// per K-tile, zero-tile skip, NT epilogue, natural (os,mt) 2D grid.
// ---------------------------------------------------------------------------
__global__ __launch_bounds__(512) void gm_gemm(
        const u16* __restrict__ xb, const u16* __restrict__ hb,
        const u16* __restrict__ Wb2, float* __restrict__ out) {
    __shared__ u16 smem[65536];   // 128 KB: As [2][2][8192] | Bs [2][2][8192]
    u16* Asb = smem;
    u16* Bsb = smem + 32768;

    int os = blockIdx.x;
    int mt = blockIdx.y;
    int mbase = mt * 256;
    const u16* wb = Wb2 + (size_t)os * (256 * KT2);
    int cb0 = ((2 * os + 25) * BSZ) & (INF - 1);

    int t = threadIdx.x;
    int lane = t & 63, w = t >> 6;
    int wr = w >> 2, wc = w & 3;
    int lr = lane & 15, g4 = lane >> 4;

    int sl = t & 7, row0 = t >> 3;
    int swo = (sl ^ (row0 & 7)) << 3;
    const u16* xa  = xb + (size_t)(mbase + row0) * INF + swo;
    const u16* ha  = hb + (size_t)(mbase + row0) * LRK + swo;
    const u16* wba = wb + (size_t)row0 * KT2 + swo;
    u16* AsD = Asb + t * 8;
    u16* BsD = Bsb + t * 8;

#define STAGE_A_(Tn, SD, H) do {                                            \
    u16* d_ = AsD + (SD) * 16384 + (H) * 8192;                              \
    if ((Tn) < 18) {                                                        \
        int colT_ = (cb0 + (Tn) * 64) & (INF - 1);                          \
        async16(xa + (size_t)((H) * 128) * INF + colT_, d_);                \
        async16(xa + (size_t)((H) * 128 + 64) * INF + colT_, d_ + 4096);    \
    } else {                                                                \
        async16(ha + (H) * 128 * LRK, d_);                                  \
        async16(ha + ((H) * 128 + 64) * LRK, d_ + 4096);                    \
    }                                                                       \
} while (0)
#define STAGE_B_(Tn, SD, H) do {                                            \
    u16* d_ = BsD + (SD) * 16384 + (H) * 8192;                              \
    async16(wba + (size_t)((H) * 128) * KT2 + (Tn) * 64, d_);               \
    async16(wba + (size_t)((H) * 128 + 64) * KT2 + (Tn) * 64, d_ + 4096);   \
} while (0)

    int arow = (wr * 64 + lr) * 64;
    int brow = (wc * 32 + lr) * 64;
    int ksw0 = ((g4) ^ (lr & 7)) << 3;
    int ksw1 = ((4 + g4) ^ (lr & 7)) << 3;

    f32x4 acc[2][2][4][2];
#pragma unroll
    for (int p = 0; p < 2; ++p)
#pragma unroll
        for (int q = 0; q < 2; ++q)
#pragma unroll
            for (int m = 0; m < 4; ++m)
#pragma unroll
                for (int n = 0; n < 2; ++n) acc[p][q][m][n] = (f32x4){0,0,0,0};

    bf16x8 a0k0 = {}, a1k0 = {}, a2k0 = {}, a3k0 = {};
    bf16x8 a0k1 = {}, a1k1 = {}, a2k1 = {}, a3k1 = {};
    bf16x8 p0k0 = {}, p1k0 = {}, p0k1 = {}, p1k1 = {};
    bf16x8 q0k0 = {}, q1k0 = {}, q0k1 = {}, q1k1 = {};

#define READ_A(S, H) do {                                                    \
    const u16* Ab_ = Asb + (S) * 16384 + (H) * 8192;                         \
    a0k0 = *(const bf16x8*)(Ab_ + arow + 0 * 1024 + ksw0);                   \
    a1k0 = *(const bf16x8*)(Ab_ + arow + 1 * 1024 + ksw0);                   \
    a2k0 = *(const bf16x8*)(Ab_ + arow + 2 * 1024 + ksw0);                   \
    a3k0 = *(const bf16x8*)(Ab_ + arow + 3 * 1024 + ksw0);                   \
    a0k1 = *(const bf16x8*)(Ab_ + arow + 0 * 1024 + ksw1);                   \
    a1k1 = *(const bf16x8*)(Ab_ + arow + 1 * 1024 + ksw1);                   \
    a2k1 = *(const bf16x8*)(Ab_ + arow + 2 * 1024 + ksw1);                   \
    a3k1 = *(const bf16x8*)(Ab_ + arow + 3 * 1024 + ksw1);                   \
} while (0)
#define READ_B0(S) do {                                                      \
    const u16* Bb_ = Bsb + (S) * 16384;                                      \
    p0k0 = *(const bf16x8*)(Bb_ + brow + 0 * 1024 + ksw0);                   \
    p1k0 = *(const bf16x8*)(Bb_ + brow + 1 * 1024 + ksw0);                   \
    p0k1 = *(const bf16x8*)(Bb_ + brow + 0 * 1024 + ksw1);                   \
    p1k1 = *(const bf16x8*)(Bb_ + brow + 1 * 1024 + ksw1);                   \
} while (0)
#define READ_B1(S) do {                                                      \
    const u16* Bb_ = Bsb + (S) * 16384 + 8192;                               \
    q0k0 = *(const bf16x8*)(Bb_ + brow + 0 * 1024 + ksw0);                   \
    q1k0 = *(const bf16x8*)(Bb_ + brow + 1 * 1024 + ksw0);                   \
    q0k1 = *(const bf16x8*)(Bb_ + brow + 0 * 1024 + ksw1);                   \
    q1k1 = *(const bf16x8*)(Bb_ + brow + 1 * 1024 + ksw1);                   \
} while (0)

#define SYNC(VMC)                                                            \
    asm volatile("s_waitcnt vmcnt(" VMC ")" ::: "memory");                   \
    FENCE(); __builtin_amdgcn_s_barrier(); FENCE();

#define MFMA16Q(MH, NH, B0, B1, B2, B3)                                      \
    __builtin_amdgcn_s_setprio(1);                                           \
    acc[MH][NH][0][0] = __builtin_amdgcn_mfma_f32_16x16x32_bf16(a0k0, B0, acc[MH][NH][0][0], 0,0,0); \
    acc[MH][NH][0][1] = __builtin_amdgcn_mfma_f32_16x16x32_bf16(a0k0, B1, acc[MH][NH][0][1], 0,0,0); \
    acc[MH][NH][1][0] = __builtin_amdgcn_mfma_f32_16x16x32_bf16(a1k0, B0, acc[MH][NH][1][0], 0,0,0); \
    acc[MH][NH][1][1] = __builtin_amdgcn_mfma_f32_16x16x32_bf16(a1k0, B1, acc[MH][NH][1][1], 0,0,0); \
    acc[MH][NH][2][0] = __builtin_amdgcn_mfma_f32_16x16x32_bf16(a2k0, B0, acc[MH][NH][2][0], 0,0,0); \
    acc[MH][NH][2][1] = __builtin_amdgcn_mfma_f32_16x16x32_bf16(a2k0, B1, acc[MH][NH][2][1], 0,0,0); \
    acc[MH][NH][3][0] = __builtin_amdgcn_mfma_f32_16x16x32_bf16(a3k0, B0, acc[MH][NH][3][0], 0,0,0); \
    acc[MH][NH][3][1] = __builtin_amdgcn_mfma_f32_16x16x32_bf16(a3k0, B1, acc[MH][NH][3][1], 0,0,0); \
    acc[MH][NH][0][0] = __builtin_amdgcn_mfma_f32_16x16x32_bf16(a0k1, B2, acc[MH][NH][0][0], 0,0,0); \
    acc[MH][NH][0][1] = __builtin_amdgcn_mfma_f32_16x16x32_bf16(a0k1, B3, acc[MH][NH][0][1], 0,0,0); \
    acc[MH][NH][1][0] = __builtin_amdgcn_mfma_f32_16x16x32_bf16(a1k1, B2, acc[MH][NH][1][0], 0,0,0); \
    acc[MH][NH][1][1] = __builtin_amdgcn_mfma_f32_16x16x32_bf16(a1k1, B3, acc[MH][NH][1][1], 0,0,0); \
    acc[MH][NH][2][0] = __builtin_amdgcn_mfma_f32_16x16x32_bf16(a2k1, B2, acc[MH][NH][2][0], 0,0,0); \
    acc[MH][NH][2][1] = __builtin_amdgcn_mfma_f32_16x16x32_bf16(a2k1, B3, acc[MH][NH][2][1], 0,0,0); \
    acc[MH][NH][3][0] = __builtin_amdgcn_mfma_f32_16x16x32_bf16(a3k1, B2, acc[MH][NH][3][0], 0,0,0); \
    acc[MH][NH][3][1] = __builtin_amdgcn_mfma_f32_16x16x32_bf16(a3k1, B3, acc[MH][NH][3][1], 0,0,0); \
    __builtin_amdgcn_s_setprio(0);

#define GROUP_G(S, TN, H0, H1) do {                                          \
    READ_A(S, 0);                                                            \
    if (H0) { READ_B0(S); }                                                  \
    STAGE_B_((TN), (S) ^ 1, 0);                                              \
    SYNC("4")                                                                \
    if (H0) { MFMA16Q(0, 0, p0k0, p1k0, p0k1, p1k1) }                        \
    if (H1) { READ_B1(S); }                                                  \
    STAGE_A_((TN), (S) ^ 1, 0);                                              \
    SYNC("4")                                                                \
    if (H1) { MFMA16Q(0, 1, q0k0, q1k0, q0k1, q1k1) }                        \
    READ_A(S, 1);                                                            \
    STAGE_B_((TN), (S) ^ 1, 1);                                              \
    SYNC("4")                                                                \
    if (H1) { MFMA16Q(1, 1, q0k0, q1k0, q0k1, q1k1) }                        \
    STAGE_A_((TN), (S) ^ 1, 1);                                              \
    SYNC("4")                                                                \
    if (H0) { MFMA16Q(1, 0, p0k0, p1k0, p0k1, p1k1) }                        \
} while (0)

#define GROUP_TAIL(S) do {                                                   \
    SYNC("0")                                                                \
    READ_A(S, 0); READ_B0(S);                                                \
    MFMA16Q(0, 0, p0k0, p1k0, p0k1, p1k1)                                    \
    READ_B1(S);                                                              \
    MFMA16Q(0, 1, q0k0, q1k0, q0k1, q1k1)                                    \
    READ_A(S, 1);                                                            \
    MFMA16Q(1, 1, q0k0, q1k0, q0k1, q1k1)                                    \
    MFMA16Q(1, 0, p0k0, p1k0, p0k1, p1k1)                                    \
} while (0)

    STAGE_B_(0, 0, 0); STAGE_A_(0, 0, 0); STAGE_B_(0, 0, 1); STAGE_A_(0, 0, 1);
    SYNC("4")

    GROUP_G(0, 1, 1, 0);                     // T=0  (half1 zero)
    GROUP_G(1, 2, 1, 0);                     // T=1  (half1 zero)
#pragma unroll 1
    for (int T = 2; T < 16; T += 2) {
        GROUP_G(0, T + 1, 1, 1);
        GROUP_G(1, T + 2, 1, 1);
    }
    GROUP_G(0, 17, 0, 1);                    // T=16 (half0 zero)
    GROUP_G(1, 18, 0, 1);                    // T=17 (half0 zero), stages LR
    GROUP_TAIL(0);                           // T=18 (lowrank, both)

    // ---- epilogue: LDS transpose -> full-line NON-TEMPORAL dwordx4 stores
    float* eb = (float*)smem;                // 128 x 256 f32 per chunk
#pragma unroll
    for (int mh = 0; mh < 2; ++mh) {
        __syncthreads();
#pragma unroll
        for (int nh = 0; nh < 2; ++nh)
#pragma unroll
            for (int m = 0; m < 4; ++m)
#pragma unroll
                for (int n = 0; n < 2; ++n)
#pragma unroll
                    for (int j = 0; j < 4; ++j) {
                        int r_ = wr * 64 + m * 16 + (g4 << 2) + j;
                        int c_ = nh * 128 + wc * 32 + n * 16 + lr;
                        eb[r_ * 256 + (((c_ >> 2) ^ ((r_ & 15) << 2)) << 2)
                           + (c_ & 3)] = acc[mh][nh][m][n][j];
                    }
        __syncthreads();
#pragma unroll
        for (int pq = 0; pq < 16; ++pq) {
            int p = pq & 3, q = pq >> 2;
            int r_ = (t >> 4) + q * 32;
            int g = (t & 15) + p * 16;
            f32x4 v = *(const f32x4*)&eb[r_ * 256
                        + ((g ^ ((r_ & 15) << 2)) << 2)];
            __builtin_nontemporal_store(v,
                (f32x4*)&out[(size_t)(mbase + mh * 128 + r_) * OUTF
                             + os * 256 + g * 4]);
        }
    }
#undef STAGE_A_
#undef STAGE_B_
#undef READ_A
#undef READ_B0
#undef READ_B1
#undef SYNC
#undef MFMA16Q
#undef GROUP_G
#undef GROUP_TAIL
}

extern "C" void kernel_launch(void* const* d_in, const int* in_sizes, int n_in,
                              void* d_out, int out_size, void* d_ws, size_t ws_size,
                              hipStream_t stream) {
    const float* x  = (const float*)d_in[0];   // [8192][4096]
    const float* W  = (const float*)d_in[1];   // [4096][8][128]
    const float* L1 = (const float*)d_in[2];   // [64][4096]
    const float* L2 = (const float*)d_in[3];   // [4096][64]
    float* out = (float*)d_out;

    char* ws = (char*)d_ws;
    u16* xb  = (u16*)(ws);                       // 67108864 B
    u16* hb  = (u16*)(ws + 67108864);            // 1048576 B
    u16* Wb2 = (u16*)(ws + 68157440);            // 13107200 B
    u16* L1b = (u16*)(ws + 81264640);            // 524288 B

    gm_l1b<<<dim3(256), dim3(256), 0, stream>>>(L1, L1b);
    gm_main<<<dim3(800), dim3(256), 0, stream>>>(x, W, L2, L1b, xb, hb, Wb2);
    gm_gemm<<<dim3(16, 32), dim3(512), 0, stream>>>(xb, hb, Wb2, out);
}

// Round 19
// 136.832 us; speedup vs baseline: 1.0028x; 1.0028x over previous
//
#include <hip/hip_runtime.h>
#include <stdint.h>

typedef unsigned short u16;
typedef short bf16x8 __attribute__((ext_vector_type(8)));
typedef float f32x4 __attribute__((ext_vector_type(4)));

#define ABI 8
#define BSZ 128
#define INF 4096
#define OUTF 4096
#define LRK 64
#define KT2 1280          // Wb2 row stride; k layout: band + [1152,1216) LR
#define NST 16

__device__ __forceinline__ u16 f2bf(float f) {
    uint32_t u = __float_as_uint(f);
    u += 0x7fffu + ((u >> 16) & 1u);
    return (u16)(u >> 16);
}

__device__ __forceinline__ uint32_t pk2(float a, float b) {
    uint32_t r;
    asm("v_cvt_pk_bf16_f32 %0, %1, %2" : "=v"(r) : "v"(a), "v"(b));
    return r;
}

__device__ __forceinline__ void async16(const u16* g, u16* l) {
    __builtin_amdgcn_global_load_lds(
        (const __attribute__((address_space(1))) uint32_t*)g,
        (__attribute__((address_space(3))) uint32_t*)l, 16, 0, 0);
}

#define FENCE() asm volatile("" ::: "memory")

// ---------------------------------------------------------------------------
// Kernel 1: L1 -> L1b bf16 (tiny; precedes gm_main which reads L1b).
// ---------------------------------------------------------------------------
__global__ __launch_bounds__(256) void gm_l1b(
        const float* __restrict__ L1, u16* __restrict__ L1b) {
    int idx = (blockIdx.x * 256 + threadIdx.x) * 4;
    f32x4 v = *reinterpret_cast<const f32x4*>(L1 + idx);
    uint32_t lo = pk2(v[0], v[1]);
    uint32_t hi = pk2(v[2], v[3]);
    *reinterpret_cast<uint32_t*>(L1b + idx)     = lo;
    *reinterpret_cast<uint32_t*>(L1b + idx + 2) = hi;
}

// ---------------------------------------------------------------------------
// Kernel 2: merged pack + cast. Cast role: 1-deep prefetch PINNED EARLY via
// __builtin_amdgcn_sched_barrier(0) — the hard scheduling fence the load-
// sinker cannot cross (r13/r18 failures were the scheduler sinking the
// prefetch loads to just-before-use; VGPR stayed 44). (256,2) bounds give
// the ~76-VGPR live set headroom at the grid-capped 2 blocks/CU.
// bid [0,256): W transpose | [256,288): L2 pack | [288,800): cast+h.
// ---------------------------------------------------------------------------
__global__ __launch_bounds__(256, 2) void gm_main(
        const float* __restrict__ x, const float* __restrict__ W,
        const float* __restrict__ L2, const u16* __restrict__ L1b,
        u16* __restrict__ xb, u16* __restrict__ hb, u16* __restrict__ Wb2) {
    __shared__ char shm[32768];
    int bid = blockIdx.x;
    int t = threadIdx.x;
    if (bid < 256) {
        u16* tile = (u16*)shm;                 // 128*128 u16 = 32 KB
        int j = bid & 7, o = bid >> 3;
        int os = o >> 1, hh = o & 1;
        int i = (o + 25 + j) & 31;             // (o-7+j) mod 32
        int a = 7 - j;
        int c = t & 127, b0 = t >> 7;          // b0: 0..1
        const float* src = W + ((size_t)(i * BSZ) * ABI + a) * BSZ + c;
#pragma unroll 4
        for (int p = 0; p < 64; ++p) {
            int b = p * 2 + b0;
            tile[b * 128 + (c ^ ((b & 31) << 1))] =
                f2bf(src[(size_t)b * (ABI * BSZ)]);
        }
        __syncthreads();
        int b = t & 127, c0 = t >> 7;
        u16* dst = Wb2 + ((size_t)os * 256 + hh * 128) * KT2
                 + (size_t)(hh * 128 + j * 128 + b);
#pragma unroll 4
        for (int p = 0; p < 64; ++p) {
            int cc = p * 2 + c0;
            dst[(size_t)cc * KT2] = tile[b * 128 + (cc ^ ((b & 31) << 1))];
        }
    } else if (bid < 288) {
        int o = bid - 256;
        int os = o >> 1, hh = o & 1;
        int r = t & 63, c0 = t >> 6;           // c0: 0..3
#pragma unroll 4
        for (int p = 0; p < 32; ++p) {
            int c = p * 4 + c0;
            Wb2[((size_t)os * 256 + hh * 128 + c) * KT2 + 1152 + r] =
                f2bf(L2[((size_t)o * BSZ + c) * LRK + r]);
        }
    } else {
        // ---- cast role: issue next-iter loads, HARD FENCE, then compute.
        float* red = (float*)shm;              // [4][4][256] = 16 KB
        int w = t >> 6, lane = t & 63;
        int lr = lane & 15, lk = (lane >> 4) << 3;
        int rb = (bid - 288) * 16;
        int row = rb + lr;
        const float* xp = x + (size_t)row * INF + w * 1024 + lk;
        u16* xo = xb + (size_t)row * INF + w * 1024 + lk;
        const u16* lp = L1b + (size_t)lr * INF + w * 1024 + lk;
        f32x4 acc[4];
#pragma unroll
        for (int ni = 0; ni < 4; ++ni) acc[ni] = (f32x4){0.f, 0.f, 0.f, 0.f};
        f32x4 c0 = *(const f32x4*)xp;
        f32x4 c1 = *(const f32x4*)(xp + 4);
        bf16x8 bv0 = *(const bf16x8*)(lp + 0 * 16 * INF);
        bf16x8 bv1 = *(const bf16x8*)(lp + 1 * 16 * INF);
        bf16x8 bv2 = *(const bf16x8*)(lp + 2 * 16 * INF);
        bf16x8 bv3 = *(const bf16x8*)(lp + 3 * 16 * INF);
#pragma unroll 1
        for (int ks = 0; ks < 32; ++ks) {
            f32x4 n0 = c0, n1 = c1;
            bf16x8 nb0 = bv0, nb1 = bv1, nb2 = bv2, nb3 = bv3;
            if (ks < 31) {
                const float* xn = xp + (ks + 1) * 32;
                n0 = *(const f32x4*)xn;
                n1 = *(const f32x4*)(xn + 4);
                const u16* ln = lp + (ks + 1) * 32;
                nb0 = *(const bf16x8*)(ln + 0 * 16 * INF);
                nb1 = *(const bf16x8*)(ln + 1 * 16 * INF);
                nb2 = *(const bf16x8*)(ln + 2 * 16 * INF);
                nb3 = *(const bf16x8*)(ln + 3 * 16 * INF);
            }
            __builtin_amdgcn_sched_barrier(0);   // loads may NOT sink past here
            union { bf16x8 v; uint32_t u[4]; } af;
            af.u[0] = pk2(c0[0], c0[1]);
            af.u[1] = pk2(c0[2], c0[3]);
            af.u[2] = pk2(c1[0], c1[1]);
            af.u[3] = pk2(c1[2], c1[3]);
            *reinterpret_cast<bf16x8*>(xo + ks * 32) = af.v;
            acc[0] = __builtin_amdgcn_mfma_f32_16x16x32_bf16(af.v, bv0, acc[0], 0, 0, 0);
            acc[1] = __builtin_amdgcn_mfma_f32_16x16x32_bf16(af.v, bv1, acc[1], 0, 0, 0);
            acc[2] = __builtin_amdgcn_mfma_f32_16x16x32_bf16(af.v, bv2, acc[2], 0, 0, 0);
            acc[3] = __builtin_amdgcn_mfma_f32_16x16x32_bf16(af.v, bv3, acc[3], 0, 0, 0);
            c0 = n0; c1 = n1;
            bv0 = nb0; bv1 = nb1; bv2 = nb2; bv3 = nb3;
        }
#pragma unroll
        for (int ni = 0; ni < 4; ++ni)
#pragma unroll
            for (int j = 0; j < 4; ++j)
                red[(w * 4 + ni) * 256 + lane * 4 + j] = acc[ni][j];
        __syncthreads();
        if (t < 64) {
#pragma unroll
            for (int ni = 0; ni < 4; ++ni)
#pragma unroll
                for (int j = 0; j < 4; ++j) {
                    float s = red[(0 * 4 + ni) * 256 + t * 4 + j]
                            + red[(1 * 4 + ni) * 256 + t * 4 + j]
                            + red[(2 * 4 + ni) * 256 + t * 4 + j]
                            + red[(3 * 4 + ni) * 256 + t * 4 + j];
                    int r_ = rb + ((t >> 4) << 2) + j;
                    int c_ = ni * 16 + (t & 15);
                    hb[(size_t)r_ * LRK + c_] = f2bf(s);
                }
        }
    }
}

// ---------------------------------------------------------------------------
// Kernel 3: 256x256 GEMM — EXACT r14/r17 version (best measured). 4-phase
// per K-tile, zero-tile skip, NT epilogue, natural (os,mt) 2D grid.
// ---------------------------------------------------------------------------
__global__ __launch_bounds__(512) void gm_gemm(
        const u16* __restrict__ xb, const u16* __restrict__ hb,
        const u16* __restrict__ Wb2, float* __restrict__ out) {
    __shared__ u16 smem[65536];   // 128 KB: As [2][2][8192] | Bs [2][2][8192]
    u16* Asb = smem;
    u16* Bsb = smem + 32768;

    int os = blockIdx.x;
    int mt = blockIdx.y;
    int mbase = mt * 256;
    const u16* wb = Wb2 + (size_t)os * (256 * KT2);
    int cb0 = ((2 * os + 25) * BSZ) & (INF - 1);

    int t = threadIdx.x;
    int lane = t & 63, w = t >> 6;
    int wr = w >> 2, wc = w & 3;
    int lr = lane & 15, g4 = lane >> 4;

    int sl = t & 7, row0 = t >> 3;
    int swo = (sl ^ (row0 & 7)) << 3;
    const u16* xa  = xb + (size_t)(mbase + row0) * INF + swo;
    const u16* ha  = hb + (size_t)(mbase + row0) * LRK + swo;
    const u16* wba = wb + (size_t)row0 * KT2 + swo;
    u16* AsD = Asb + t * 8;
    u16* BsD = Bsb + t * 8;

#define STAGE_A_(Tn, SD, H) do {                                            \
    u16* d_ = AsD + (SD) * 16384 + (H) * 8192;                              \
    if ((Tn) < 18) {                                                        \
        int colT_ = (cb0 + (Tn) * 64) & (INF - 1);                          \
        async16(xa + (size_t)((H) * 128) * INF + colT_, d_);                \
        async16(xa + (size_t)((H) * 128 + 64) * INF + colT_, d_ + 4096);    \
    } else {                                                                \
        async16(ha + (H) * 128 * LRK, d_);                                  \
        async16(ha + ((H) * 128 + 64) * LRK, d_ + 4096);                    \
    }                                                                       \
} while (0)
#define STAGE_B_(Tn, SD, H) do {                                            \
    u16* d_ = BsD + (SD) * 16384 + (H) * 8192;                              \
    async16(wba + (size_t)((H) * 128) * KT2 + (Tn) * 64, d_);               \
    async16(wba + (size_t)((H) * 128 + 64) * KT2 + (Tn) * 64, d_ + 4096);   \
} while (0)

    int arow = (wr * 64 + lr) * 64;
    int brow = (wc * 32 + lr) * 64;
    int ksw0 = ((g4) ^ (lr & 7)) << 3;
    int ksw1 = ((4 + g4) ^ (lr & 7)) << 3;

    f32x4 acc[2][2][4][2];
#pragma unroll
    for (int p = 0; p < 2; ++p)
#pragma unroll
        for (int q = 0; q < 2; ++q)
#pragma unroll
            for (int m = 0; m < 4; ++m)
#pragma unroll
                for (int n = 0; n < 2; ++n) acc[p][q][m][n] = (f32x4){0,0,0,0};

    bf16x8 a0k0 = {}, a1k0 = {}, a2k0 = {}, a3k0 = {};
    bf16x8 a0k1 = {}, a1k1 = {}, a2k1 = {}, a3k1 = {};
    bf16x8 p0k0 = {}, p1k0 = {}, p0k1 = {}, p1k1 = {};
    bf16x8 q0k0 = {}, q1k0 = {}, q0k1 = {}, q1k1 = {};

#define READ_A(S, H) do {                                                    \
    const u16* Ab_ = Asb + (S) * 16384 + (H) * 8192;                         \
    a0k0 = *(const bf16x8*)(Ab_ + arow + 0 * 1024 + ksw0);                   \
    a1k0 = *(const bf16x8*)(Ab_ + arow + 1 * 1024 + ksw0);                   \
    a2k0 = *(const bf16x8*)(Ab_ + arow + 2 * 1024 + ksw0);                   \
    a3k0 = *(const bf16x8*)(Ab_ + arow + 3 * 1024 + ksw0);                   \
    a0k1 = *(const bf16x8*)(Ab_ + arow + 0 * 1024 + ksw1);                   \
    a1k1 = *(const bf16x8*)(Ab_ + arow + 1 * 1024 + ksw1);                   \
    a2k1 = *(const bf16x8*)(Ab_ + arow + 2 * 1024 + ksw1);                   \
    a3k1 = *(const bf16x8*)(Ab_ + arow + 3 * 1024 + ksw1);                   \
} while (0)
#define READ_B0(S) do {                                                      \
    const u16* Bb_ = Bsb + (S) * 16384;                                      \
    p0k0 = *(const bf16x8*)(Bb_ + brow + 0 * 1024 + ksw0);                   \
    p1k0 = *(const bf16x8*)(Bb_ + brow + 1 * 1024 + ksw0);                   \
    p0k1 = *(const bf16x8*)(Bb_ + brow + 0 * 1024 + ksw1);                   \
    p1k1 = *(const bf16x8*)(Bb_ + brow + 1 * 1024 + ksw1);                   \
} while (0)
#define READ_B1(S) do {                                                      \
    const u16* Bb_ = Bsb + (S) * 16384 + 8192;                               \
    q0k0 = *(const bf16x8*)(Bb_ + brow + 0 * 1024 + ksw0);                   \
    q1k0 = *(const bf16x8*)(Bb_ + brow + 1 * 1024 + ksw0);                   \
    q0k1 = *(const bf16x8*)(Bb_ + brow + 0 * 1024 + ksw1);                   \
    q1k1 = *(const bf16x8*)(Bb_ + brow + 1 * 1024 + ksw1);                   \
} while (0)

#define SYNC(VMC)                                                            \
    asm volatile("s_waitcnt vmcnt(" VMC ")" ::: "memory");                   \
    FENCE(); __builtin_amdgcn_s_barrier(); FENCE();

#define MFMA16Q(MH, NH, B0, B1, B2, B3)                                      \
    __builtin_amdgcn_s_setprio(1);                                           \
    acc[MH][NH][0][0] = __builtin_amdgcn_mfma_f32_16x16x32_bf16(a0k0, B0, acc[MH][NH][0][0], 0,0,0); \
    acc[MH][NH][0][1] = __builtin_amdgcn_mfma_f32_16x16x32_bf16(a0k0, B1, acc[MH][NH][0][1], 0,0,0); \
    acc[MH][NH][1][0] = __builtin_amdgcn_mfma_f32_16x16x32_bf16(a1k0, B0, acc[MH][NH][1][0], 0,0,0); \
    acc[MH][NH][1][1] = __builtin_amdgcn_mfma_f32_16x16x32_bf16(a1k0, B1, acc[MH][NH][1][1], 0,0,0); \
    acc[MH][NH][2][0] = __builtin_amdgcn_mfma_f32_16x16x32_bf16(a2k0, B0, acc[MH][NH][2][0], 0,0,0); \
    acc[MH][NH][2][1] = __builtin_amdgcn_mfma_f32_16x16x32_bf16(a2k0, B1, acc[MH][NH][2][1], 0,0,0); \
    acc[MH][NH][3][0] = __builtin_amdgcn_mfma_f32_16x16x32_bf16(a3k0, B0, acc[MH][NH][3][0], 0,0,0); \
    acc[MH][NH][3][1] = __builtin_amdgcn_mfma_f32_16x16x32_bf16(a3k0, B1, acc[MH][NH][3][1], 0,0,0); \
    acc[MH][NH][0][0] = __builtin_amdgcn_mfma_f32_16x16x32_bf16(a0k1, B2, acc[MH][NH][0][0], 0,0,0); \
    acc[MH][NH][0][1] = __builtin_amdgcn_mfma_f32_16x16x32_bf16(a0k1, B3, acc[MH][NH][0][1], 0,0,0); \
    acc[MH][NH][1][0] = __builtin_amdgcn_mfma_f32_16x16x32_bf16(a1k1, B2, acc[MH][NH][1][0], 0,0,0); \
    acc[MH][NH][1][1] = __builtin_amdgcn_mfma_f32_16x16x32_bf16(a1k1, B3, acc[MH][NH][1][1], 0,0,0); \
    acc[MH][NH][2][0] = __builtin_amdgcn_mfma_f32_16x16x32_bf16(a2k1, B2, acc[MH][NH][2][0], 0,0,0); \
    acc[MH][NH][2][1] = __builtin_amdgcn_mfma_f32_16x16x32_bf16(a2k1, B3, acc[MH][NH][2][1], 0,0,0); \
    acc[MH][NH][3][0] = __builtin_amdgcn_mfma_f32_16x16x32_bf16(a3k1, B2, acc[MH][NH][3][0], 0,0,0); \
    acc[MH][NH][3][1] = __builtin_amdgcn_mfma_f32_16x16x32_bf16(a3k1, B3, acc[MH][NH][3][1], 0,0,0); \
    __builtin_amdgcn_s_setprio(0);

#define GROUP_G(S, TN, H0, H1) do {                                          \
    READ_A(S, 0);                                                            \
    if (H0) { READ_B0(S); }                                                  \
    STAGE_B_((TN), (S) ^ 1, 0);                                              \
    SYNC("4")                                                                \
    if (H0) { MFMA16Q(0, 0, p0k0, p1k0, p0k1, p1k1) }                        \
    if (H1) { READ_B1(S); }                                                  \
    STAGE_A_((TN), (S) ^ 1, 0);                                              \
    SYNC("4")                                                                \
    if (H1) { MFMA16Q(0, 1, q0k0, q1k0, q0k1, q1k1) }                        \
    READ_A(S, 1);                                                            \
    STAGE_B_((TN), (S) ^ 1, 1);                                              \
    SYNC("4")                                                                \
    if (H1) { MFMA16Q(1, 1, q0k0, q1k0, q0k1, q1k1) }                        \
    STAGE_A_((TN), (S) ^ 1, 1);                                              \
    SYNC("4")                                                                \
    if (H0) { MFMA16Q(1, 0, p0k0, p1k0, p0k1, p1k1) }                        \
} while (0)

#define GROUP_TAIL(S) do {                                                   \
    SYNC("0")                                                                \
    READ_A(S, 0); READ_B0(S);                                                \
    MFMA16Q(0, 0, p0k0, p1k0, p0k1, p1k1)                                    \
    READ_B1(S);                                                              \
    MFMA16Q(0, 1, q0k0, q1k0, q0k1, q1k1)                                    \
    READ_A(S, 1);                                                            \
    MFMA16Q(1, 1, q0k0, q1k0, q0k1, q1k1)                                    \
    MFMA16Q(1, 0, p0k0, p1k0, p0k1, p1k1)                                    \
} while (0)

    STAGE_B_(0, 0, 0); STAGE_A_(0, 0, 0); STAGE_B_(0, 0, 1); STAGE_A_(0, 0, 1);
    SYNC("4")

    GROUP_G(0, 1, 1, 0);                     // T=0  (half1 zero)
    GROUP_G(1, 2, 1, 0);                     // T=1  (half1 zero)
#pragma unroll 1
    for (int T = 2; T < 16; T += 2) {
        GROUP_G(0, T + 1, 1, 1);
        GROUP_G(1, T + 2, 1, 1);
    }
    GROUP_G(0, 17, 0, 1);                    // T=16 (half0 zero)
    GROUP_G(1, 18, 0, 1);                    // T=17 (half0 zero), stages LR
    GROUP_TAIL(0);                           // T=18 (lowrank, both)

    // ---- epilogue: LDS transpose -> full-line NON-TEMPORAL dwordx4 stores
    float* eb = (float*)smem;                // 128 x 256 f32 per chunk
#pragma unroll
    for (int mh = 0; mh < 2; ++mh) {
        __syncthreads();
#pragma unroll
        for (int nh = 0; nh < 2; ++nh)
#pragma unroll
            for (int m = 0; m < 4; ++m)
#pragma unroll
                for (int n = 0; n < 2; ++n)
#pragma unroll
                    for (int j = 0; j < 4; ++j) {
                        int r_ = wr * 64 + m * 16 + (g4 << 2) + j;
                        int c_ = nh * 128 + wc * 32 + n * 16 + lr;
                        eb[r_ * 256 + (((c_ >> 2) ^ ((r_ & 15) << 2)) << 2)
                           + (c_ & 3)] = acc[mh][nh][m][n][j];
                    }
        __syncthreads();
#pragma unroll
        for (int pq = 0; pq < 16; ++pq) {
            int p = pq & 3, q = pq >> 2;
            int r_ = (t >> 4) + q * 32;
            int g = (t & 15) + p * 16;
            f32x4 v = *(const f32x4*)&eb[r_ * 256
                        + ((g ^ ((r_ & 15) << 2)) << 2)];
            __builtin_nontemporal_store(v,
                (f32x4*)&out[(size_t)(mbase + mh * 128 + r_) * OUTF
                             + os * 256 + g * 4]);
        }
    }
#undef STAGE_A_
#undef STAGE_B_
#undef READ_A
#undef READ_B0
#undef READ_B1
#undef SYNC
#undef MFMA16Q
#undef GROUP_G
#undef GROUP_TAIL
}

extern "C" void kernel_launch(void* const* d_in, const int* in_sizes, int n_in,
                              void* d_out, int out_size, void* d_ws, size_t ws_size,
                              hipStream_t stream) {
    const float* x  = (const float*)d_in[0];   // [8192][4096]
    const float* W  = (const float*)d_in[1];   // [4096][8][128]
    const float* L1 = (const float*)d_in[2];   // [64][4096]
    const float* L2 = (const float*)d_in[3];   // [4096][64]
    float* out = (float*)d_out;

    char* ws = (char*)d_ws;
    u16* xb  = (u16*)(ws);                       // 67108864 B
    u16* hb  = (u16*)(ws + 67108864);            // 1048576 B
    u16* Wb2 = (u16*)(ws + 68157440);            // 13107200 B
    u16* L1b = (u16*)(ws + 81264640);            // 524288 B

    gm_l1b<<<dim3(256), dim3(256), 0, stream>>>(L1, L1b);
    gm_main<<<dim3(800), dim3(256), 0, stream>>>(x, W, L2, L1b, xb, hb, Wb2);
    gm_gemm<<<dim3(16, 32), dim3(512), 0, stream>>>(xb, hb, Wb2, out);
}

// Round 21
// 136.131 us; speedup vs baseline: 1.0080x; 1.0052x over previous
//
#include <hip/hip_runtime.h>
#include <stdint.h>

typedef unsigned short u16;
typedef short bf16x8 __attribute__((ext_vector_type(8)));
typedef float f32x4 __attribute__((ext_vector_type(4)));

#define ABI 8
#define BSZ 128
#define INF 4096
#define OUTF 4096
#define LRK 64
#define KT2 1280          // Wb2 row stride; k layout: band + [1152,1216) LR
#define NST 16

__device__ __forceinline__ u16 f2bf(float f) {
    uint32_t u = __float_as_uint(f);
    u += 0x7fffu + ((u >> 16) & 1u);
    return (u16)(u >> 16);
}

__device__ __forceinline__ uint32_t pk2(float a, float b) {
    uint32_t r;
    asm("v_cvt_pk_bf16_f32 %0, %1, %2" : "=v"(r) : "v"(a), "v"(b));
    return r;
}

__device__ __forceinline__ void async16(const u16* g, u16* l) {
    __builtin_amdgcn_global_load_lds(
        (const __attribute__((address_space(1))) uint32_t*)g,
        (__attribute__((address_space(3))) uint32_t*)l, 16, 0, 0);
}

#define FENCE() asm volatile("" ::: "memory")

// ---------------------------------------------------------------------------
// Kernel 1: L1 -> L1b bf16 (tiny; must precede gm_main which reads L1b).
// 256 blocks x 256 thr x 4 elems = 262144.
// ---------------------------------------------------------------------------
__global__ __launch_bounds__(256) void gm_l1b(
        const float* __restrict__ L1, u16* __restrict__ L1b) {
    int idx = (blockIdx.x * 256 + threadIdx.x) * 4;
    f32x4 v = *reinterpret_cast<const f32x4*>(L1 + idx);
    uint32_t lo = pk2(v[0], v[1]);
    uint32_t hi = pk2(v[2], v[3]);
    *reinterpret_cast<uint32_t*>(L1b + idx)     = lo;
    *reinterpret_cast<uint32_t*>(L1b + idx + 2) = hi;
}

// ---------------------------------------------------------------------------
// Kernel 2: merged pack + cast (data-independent roles; pack blocks first so
// they co-reside with / hide under the latency-bound cast blocks).
// bid [0,256):   W 128x128 tile transpose (r7-validated 256-thr body)
// bid [256,288): L2 lowrank pack -> Wb2 k[1152,1216)
// bid [288,800): fused cast+h (r12/r14-validated body), rb=(bid-288)*16
// NOTE: no prefetch in the cast loop — 4 attempts (r8/r13/r18/r19/r20 asm)
// all failed or crashed; compiler load-sinking is structural at HIP level.
// ---------------------------------------------------------------------------
__global__ __launch_bounds__(256) void gm_main(
        const float* __restrict__ x, const float* __restrict__ W,
        const float* __restrict__ L2, const u16* __restrict__ L1b,
        u16* __restrict__ xb, u16* __restrict__ hb, u16* __restrict__ Wb2) {
    __shared__ char shm[32768];
    int bid = blockIdx.x;
    int t = threadIdx.x;
    if (bid < 256) {
        u16* tile = (u16*)shm;                 // 128*128 u16 = 32 KB
        int j = bid & 7, o = bid >> 3;
        int os = o >> 1, hh = o & 1;
        int i = (o + 25 + j) & 31;             // (o-7+j) mod 32
        int a = 7 - j;
        int c = t & 127, b0 = t >> 7;          // b0: 0..1
        const float* src = W + ((size_t)(i * BSZ) * ABI + a) * BSZ + c;
#pragma unroll 4
        for (int p = 0; p < 64; ++p) {
            int b = p * 2 + b0;
            tile[b * 128 + (c ^ ((b & 31) << 1))] =
                f2bf(src[(size_t)b * (ABI * BSZ)]);
        }
        __syncthreads();
        int b = t & 127, c0 = t >> 7;
        u16* dst = Wb2 + ((size_t)os * 256 + hh * 128) * KT2
                 + (size_t)(hh * 128 + j * 128 + b);
#pragma unroll 4
        for (int p = 0; p < 64; ++p) {
            int cc = p * 2 + c0;
            dst[(size_t)cc * KT2] = tile[b * 128 + (cc ^ ((b & 31) << 1))];
        }
    } else if (bid < 288) {
        int o = bid - 256;
        int os = o >> 1, hh = o & 1;
        int r = t & 63, c0 = t >> 6;           // c0: 0..3
#pragma unroll 4
        for (int p = 0; p < 32; ++p) {
            int c = p * 4 + c0;
            Wb2[((size_t)os * 256 + hh * 128 + c) * KT2 + 1152 + r] =
                f2bf(L2[((size_t)o * BSZ + c) * LRK + r]);
        }
    } else {
        // ---- cast role: r12/r14 body verbatim
        float* red = (float*)shm;              // [4][4][256] = 16 KB
        int w = t >> 6, lane = t & 63;
        int lr = lane & 15, lk = (lane >> 4) << 3;
        int rb = (bid - 288) * 16;
        int row = rb + lr;
        f32x4 acc[4];
#pragma unroll
        for (int ni = 0; ni < 4; ++ni) acc[ni] = (f32x4){0.f, 0.f, 0.f, 0.f};
        const int k_base = w * 1024;
        for (int ks = 0; ks < 32; ++ks) {
            int k0 = k_base + ks * 32 + lk;
            const float* xp = x + (size_t)row * INF + k0;
            f32x4 x0 = *reinterpret_cast<const f32x4*>(xp);
            f32x4 x1 = *reinterpret_cast<const f32x4*>(xp + 4);
            union { bf16x8 v; uint32_t u[4]; } af;
            af.u[0] = pk2(x0[0], x0[1]);
            af.u[1] = pk2(x0[2], x0[3]);
            af.u[2] = pk2(x1[0], x1[1]);
            af.u[3] = pk2(x1[2], x1[3]);
            *reinterpret_cast<bf16x8*>(xb + (size_t)row * INF + k0) = af.v;
#pragma unroll
            for (int ni = 0; ni < 4; ++ni) {
                bf16x8 bv = *reinterpret_cast<const bf16x8*>(
                    L1b + (size_t)(ni * 16 + lr) * INF + k0);
                acc[ni] = __builtin_amdgcn_mfma_f32_16x16x32_bf16(af.v, bv, acc[ni], 0, 0, 0);
            }
        }
#pragma unroll
        for (int ni = 0; ni < 4; ++ni)
#pragma unroll
            for (int j = 0; j < 4; ++j)
                red[(w * 4 + ni) * 256 + lane * 4 + j] = acc[ni][j];
        __syncthreads();
        if (t < 64) {
#pragma unroll
            for (int ni = 0; ni < 4; ++ni)
#pragma unroll
                for (int j = 0; j < 4; ++j) {
                    float s = red[(0 * 4 + ni) * 256 + t * 4 + j]
                            + red[(1 * 4 + ni) * 256 + t * 4 + j]
                            + red[(2 * 4 + ni) * 256 + t * 4 + j]
                            + red[(3 * 4 + ni) * 256 + t * 4 + j];
                    int r_ = rb + ((t >> 4) << 2) + j;
                    int c_ = ni * 16 + (t & 15);
                    hb[(size_t)r_ * LRK + c_] = f2bf(s);
                }
        }
    }
}

// ---------------------------------------------------------------------------
// Kernel 3: 256x256 GEMM — EXACT r14/r17 version (best measured; natural
// (os,mt) 2D grid, 4-phase per K-tile, zero-tile skip, NT epilogue).
// 8 waves (2Mx4N).
// ---------------------------------------------------------------------------
__global__ __launch_bounds__(512) void gm_gemm(
        const u16* __restrict__ xb, const u16* __restrict__ hb,
        const u16* __restrict__ Wb2, float* __restrict__ out) {
    __shared__ u16 smem[65536];   // 128 KB: As [2][2][8192] | Bs [2][2][8192]
    u16* Asb = smem;
    u16* Bsb = smem + 32768;

    int os = blockIdx.x;
    int mt = blockIdx.y;
    int mbase = mt * 256;
    const u16* wb = Wb2 + (size_t)os * (256 * KT2);
    int cb0 = ((2 * os + 25) * BSZ) & (INF - 1);

    int t = threadIdx.x;
    int lane = t & 63, w = t >> 6;
    int wr = w >> 2, wc = w & 3;
    int lr = lane & 15, g4 = lane >> 4;

    int sl = t & 7, row0 = t >> 3;
    int swo = (sl ^ (row0 & 7)) << 3;
    const u16* xa  = xb + (size_t)(mbase + row0) * INF + swo;
    const u16* ha  = hb + (size_t)(mbase + row0) * LRK + swo;
    const u16* wba = wb + (size_t)row0 * KT2 + swo;
    u16* AsD = Asb + t * 8;
    u16* BsD = Bsb + t * 8;

#define STAGE_A_(Tn, SD, H) do {                                            \
    u16* d_ = AsD + (SD) * 16384 + (H) * 8192;                              \
    if ((Tn) < 18) {                                                        \
        int colT_ = (cb0 + (Tn) * 64) & (INF - 1);                          \
        async16(xa + (size_t)((H) * 128) * INF + colT_, d_);                \
        async16(xa + (size_t)((H) * 128 + 64) * INF + colT_, d_ + 4096);    \
    } else {                                                                \
        async16(ha + (H) * 128 * LRK, d_);                                  \
        async16(ha + ((H) * 128 + 64) * LRK, d_ + 4096);                    \
    }                                                                       \
} while (0)
#define STAGE_B_(Tn, SD, H) do {                                            \
    u16* d_ = BsD + (SD) * 16384 + (H) * 8192;                              \
    async16(wba + (size_t)((H) * 128) * KT2 + (Tn) * 64, d_);               \
    async16(wba + (size_t)((H) * 128 + 64) * KT2 + (Tn) * 64, d_ + 4096);   \
} while (0)

    int arow = (wr * 64 + lr) * 64;
    int brow = (wc * 32 + lr) * 64;
    int ksw0 = ((g4) ^ (lr & 7)) << 3;
    int ksw1 = ((4 + g4) ^ (lr & 7)) << 3;

    f32x4 acc[2][2][4][2];
#pragma unroll
    for (int p = 0; p < 2; ++p)
#pragma unroll
        for (int q = 0; q < 2; ++q)
#pragma unroll
            for (int m = 0; m < 4; ++m)
#pragma unroll
                for (int n = 0; n < 2; ++n) acc[p][q][m][n] = (f32x4){0,0,0,0};

    bf16x8 a0k0 = {}, a1k0 = {}, a2k0 = {}, a3k0 = {};
    bf16x8 a0k1 = {}, a1k1 = {}, a2k1 = {}, a3k1 = {};
    bf16x8 p0k0 = {}, p1k0 = {}, p0k1 = {}, p1k1 = {};
    bf16x8 q0k0 = {}, q1k0 = {}, q0k1 = {}, q1k1 = {};

#define READ_A(S, H) do {                                                    \
    const u16* Ab_ = Asb + (S) * 16384 + (H) * 8192;                         \
    a0k0 = *(const bf16x8*)(Ab_ + arow + 0 * 1024 + ksw0);                   \
    a1k0 = *(const bf16x8*)(Ab_ + arow + 1 * 1024 + ksw0);                   \
    a2k0 = *(const bf16x8*)(Ab_ + arow + 2 * 1024 + ksw0);                   \
    a3k0 = *(const bf16x8*)(Ab_ + arow + 3 * 1024 + ksw0);                   \
    a0k1 = *(const bf16x8*)(Ab_ + arow + 0 * 1024 + ksw1);                   \
    a1k1 = *(const bf16x8*)(Ab_ + arow + 1 * 1024 + ksw1);                   \
    a2k1 = *(const bf16x8*)(Ab_ + arow + 2 * 1024 + ksw1);                   \
    a3k1 = *(const bf16x8*)(Ab_ + arow + 3 * 1024 + ksw1);                   \
} while (0)
#define READ_B0(S) do {                                                      \
    const u16* Bb_ = Bsb + (S) * 16384;                                      \
    p0k0 = *(const bf16x8*)(Bb_ + brow + 0 * 1024 + ksw0);                   \
    p1k0 = *(const bf16x8*)(Bb_ + brow + 1 * 1024 + ksw0);                   \
    p0k1 = *(const bf16x8*)(Bb_ + brow + 0 * 1024 + ksw1);                   \
    p1k1 = *(const bf16x8*)(Bb_ + brow + 1 * 1024 + ksw1);                   \
} while (0)
#define READ_B1(S) do {                                                      \
    const u16* Bb_ = Bsb + (S) * 16384 + 8192;                               \
    q0k0 = *(const bf16x8*)(Bb_ + brow + 0 * 1024 + ksw0);                   \
    q1k0 = *(const bf16x8*)(Bb_ + brow + 1 * 1024 + ksw0);                   \
    q0k1 = *(const bf16x8*)(Bb_ + brow + 0 * 1024 + ksw1);                   \
    q1k1 = *(const bf16x8*)(Bb_ + brow + 1 * 1024 + ksw1);                   \
} while (0)

#define SYNC(VMC)                                                            \
    asm volatile("s_waitcnt vmcnt(" VMC ")" ::: "memory");                   \
    FENCE(); __builtin_amdgcn_s_barrier(); FENCE();

#define MFMA16Q(MH, NH, B0, B1, B2, B3)                                      \
    __builtin_amdgcn_s_setprio(1);                                           \
    acc[MH][NH][0][0] = __builtin_amdgcn_mfma_f32_16x16x32_bf16(a0k0, B0, acc[MH][NH][0][0], 0,0,0); \
    acc[MH][NH][0][1] = __builtin_amdgcn_mfma_f32_16x16x32_bf16(a0k0, B1, acc[MH][NH][0][1], 0,0,0); \
    acc[MH][NH][1][0] = __builtin_amdgcn_mfma_f32_16x16x32_bf16(a1k0, B0, acc[MH][NH][1][0], 0,0,0); \
    acc[MH][NH][1][1] = __builtin_amdgcn_mfma_f32_16x16x32_bf16(a1k0, B1, acc[MH][NH][1][1], 0,0,0); \
    acc[MH][NH][2][0] = __builtin_amdgcn_mfma_f32_16x16x32_bf16(a2k0, B0, acc[MH][NH][2][0], 0,0,0); \
    acc[MH][NH][2][1] = __builtin_amdgcn_mfma_f32_16x16x32_bf16(a2k0, B1, acc[MH][NH][2][1], 0,0,0); \
    acc[MH][NH][3][0] = __builtin_amdgcn_mfma_f32_16x16x32_bf16(a3k0, B0, acc[MH][NH][3][0], 0,0,0); \
    acc[MH][NH][3][1] = __builtin_amdgcn_mfma_f32_16x16x32_bf16(a3k0, B1, acc[MH][NH][3][1], 0,0,0); \
    acc[MH][NH][0][0] = __builtin_amdgcn_mfma_f32_16x16x32_bf16(a0k1, B2, acc[MH][NH][0][0], 0,0,0); \
    acc[MH][NH][0][1] = __builtin_amdgcn_mfma_f32_16x16x32_bf16(a0k1, B3, acc[MH][NH][0][1], 0,0,0); \
    acc[MH][NH][1][0] = __builtin_amdgcn_mfma_f32_16x16x32_bf16(a1k1, B2, acc[MH][NH][1][0], 0,0,0); \
    acc[MH][NH][1][1] = __builtin_amdgcn_mfma_f32_16x16x32_bf16(a1k1, B3, acc[MH][NH][1][1], 0,0,0); \
    acc[MH][NH][2][0] = __builtin_amdgcn_mfma_f32_16x16x32_bf16(a2k1, B2, acc[MH][NH][2][0], 0,0,0); \
    acc[MH][NH][2][1] = __builtin_amdgcn_mfma_f32_16x16x32_bf16(a2k1, B3, acc[MH][NH][2][1], 0,0,0); \
    acc[MH][NH][3][0] = __builtin_amdgcn_mfma_f32_16x16x32_bf16(a3k1, B2, acc[MH][NH][3][0], 0,0,0); \
    acc[MH][NH][3][1] = __builtin_amdgcn_mfma_f32_16x16x32_bf16(a3k1, B3, acc[MH][NH][3][1], 0,0,0); \
    __builtin_amdgcn_s_setprio(0);

#define GROUP_G(S, TN, H0, H1) do {                                          \
    READ_A(S, 0);                                                            \
    if (H0) { READ_B0(S); }                                                  \
    STAGE_B_((TN), (S) ^ 1, 0);                                              \
    SYNC("4")                                                                \
    if (H0) { MFMA16Q(0, 0, p0k0, p1k0, p0k1, p1k1) }                        \
    if (H1) { READ_B1(S); }                                                  \
    STAGE_A_((TN), (S) ^ 1, 0);                                              \
    SYNC("4")                                                                \
    if (H1) { MFMA16Q(0, 1, q0k0, q1k0, q0k1, q1k1) }                        \
    READ_A(S, 1);                                                            \
    STAGE_B_((TN), (S) ^ 1, 1);                                              \
    SYNC("4")                                                                \
    if (H1) { MFMA16Q(1, 1, q0k0, q1k0, q0k1, q1k1) }                        \
    STAGE_A_((TN), (S) ^ 1, 1);                                              \
    SYNC("4")                                                                \
    if (H0) { MFMA16Q(1, 0, p0k0, p1k0, p0k1, p1k1) }                        \
} while (0)

#define GROUP_TAIL(S) do {                                                   \
    SYNC("0")                                                                \
    READ_A(S, 0); READ_B0(S);                                                \
    MFMA16Q(0, 0, p0k0, p1k0, p0k1, p1k1)                                    \
    READ_B1(S);                                                              \
    MFMA16Q(0, 1, q0k0, q1k0, q0k1, q1k1)                                    \
    READ_A(S, 1);                                                            \
    MFMA16Q(1, 1, q0k0, q1k0, q0k1, q1k1)                                    \
    MFMA16Q(1, 0, p0k0, p1k0, p0k1, p1k1)                                    \
} while (0)

    STAGE_B_(0, 0, 0); STAGE_A_(0, 0, 0); STAGE_B_(0, 0, 1); STAGE_A_(0, 0, 1);
    SYNC("4")

    GROUP_G(0, 1, 1, 0);                     // T=0  (half1 zero)
    GROUP_G(1, 2, 1, 0);                     // T=1  (half1 zero)
#pragma unroll 1
    for (int T = 2; T < 16; T += 2) {
        GROUP_G(0, T + 1, 1, 1);
        GROUP_G(1, T + 2, 1, 1);
    }
    GROUP_G(0, 17, 0, 1);                    // T=16 (half0 zero)
    GROUP_G(1, 18, 0, 1);                    // T=17 (half0 zero), stages LR
    GROUP_TAIL(0);                           // T=18 (lowrank, both)

    // ---- epilogue: LDS transpose -> full-line NON-TEMPORAL dwordx4 stores
    float* eb = (float*)smem;                // 128 x 256 f32 per chunk
#pragma unroll
    for (int mh = 0; mh < 2; ++mh) {
        __syncthreads();
#pragma unroll
        for (int nh = 0; nh < 2; ++nh)
#pragma unroll
            for (int m = 0; m < 4; ++m)
#pragma unroll
                for (int n = 0; n < 2; ++n)
#pragma unroll
                    for (int j = 0; j < 4; ++j) {
                        int r_ = wr * 64 + m * 16 + (g4 << 2) + j;
                        int c_ = nh * 128 + wc * 32 + n * 16 + lr;
                        eb[r_ * 256 + (((c_ >> 2) ^ ((r_ & 15) << 2)) << 2)
                           + (c_ & 3)] = acc[mh][nh][m][n][j];
                    }
        __syncthreads();
#pragma unroll
        for (int pq = 0; pq < 16; ++pq) {
            int p = pq & 3, q = pq >> 2;
            int r_ = (t >> 4) + q * 32;
            int g = (t & 15) + p * 16;
            f32x4 v = *(const f32x4*)&eb[r_ * 256
                        + ((g ^ ((r_ & 15) << 2)) << 2)];
            __builtin_nontemporal_store(v,
                (f32x4*)&out[(size_t)(mbase + mh * 128 + r_) * OUTF
                             + os * 256 + g * 4]);
        }
    }
#undef STAGE_A_
#undef STAGE_B_
#undef READ_A
#undef READ_B0
#undef READ_B1
#undef SYNC
#undef MFMA16Q
#undef GROUP_G
#undef GROUP_TAIL
}

extern "C" void kernel_launch(void* const* d_in, const int* in_sizes, int n_in,
                              void* d_out, int out_size, void* d_ws, size_t ws_size,
                              hipStream_t stream) {
    const float* x  = (const float*)d_in[0];   // [8192][4096]
    const float* W  = (const float*)d_in[1];   // [4096][8][128]
    const float* L1 = (const float*)d_in[2];   // [64][4096]
    const float* L2 = (const float*)d_in[3];   // [4096][64]
    float* out = (float*)d_out;

    char* ws = (char*)d_ws;
    u16* xb  = (u16*)(ws);                       // 67108864 B
    u16* hb  = (u16*)(ws + 67108864);            // 1048576 B
    u16* Wb2 = (u16*)(ws + 68157440);            // 13107200 B
    u16* L1b = (u16*)(ws + 81264640);            // 524288 B

    gm_l1b<<<dim3(256), dim3(256), 0, stream>>>(L1, L1b);
    gm_main<<<dim3(800), dim3(256), 0, stream>>>(x, W, L2, L1b, xb, hb, Wb2);
    gm_gemm<<<dim3(16, 32), dim3(512), 0, stream>>>(xb, hb, Wb2, out);
}